// Round 6
// baseline (73.352 us; speedup 1.0000x reference)
//
#include <hip/hip_runtime.h>

#define B_ 64
#define T_ 1024
#define J_ 52
#define CPB 4                        // chains (waves) per block
#define ROTF (J_ * 9)                // 468 floats per chain (local rotations)
#define CMPF (J_ * 16)               // 832 floats per chain (composed 4x4)
#define POSF (J_ * 3)                // 156 floats per chain (positions)

// per-wave LDS slice layout (floats); every region base is 128B-aligned
#define ROT_OFF 0                    // 468 used, padded to 480 (1920 B)
#define CMP_OFF 480                  // 832 floats (3328 B)
#define POS_OFF 1312                 // 156 used, padded to 160 (640 B)
#define WSLICE  1472                 // 5888 B = 46*128 -> slice bases 128B-aligned

typedef float f4 __attribute__((ext_vector_type(4)));

// Involutive XOR swizzle on local byte offset: bits [4:5] ^= bits [7:8].
// Bijective within each 128B row; keeps 16B alignment.
__device__ __forceinline__ int swz(int byte) {
    return byte ^ (((byte >> 7) & 3) << 4);
}

__global__ __launch_bounds__(256) void ForwardKinematics_38543036514646_kernel(
    const float* __restrict__ rotation,   // (B,T,J,3,3)
    const float* __restrict__ position,   // (B,T,3)
    const float* __restrict__ offsets,    // (B,J,3)
    const int*   __restrict__ parents,    // (J,)
    float* __restrict__ out_pos,          // (B,T,J,3)
    float* __restrict__ out_comp)         // (B,T,J,4,4)
{
    __shared__ float lds[CPB * WSLICE];   // 23552 B; no cross-wave sharing

    const int tid  = threadIdx.x;
    const int lane = tid & 63;
    const int wv   = tid >> 6;
    const long long bt = (long long)blockIdx.x * CPB + wv;
    const int b = (int)(bt >> 10);        // T = 1024
    float* wlds = lds + wv * WSLICE;      // this wave's private slice

    // ---- stage own chain's rotations into LDS (117 f4, contiguous, nt) ----
    {
        const f4* src = (const f4*)(rotation + bt * ROTF);
        f4* dst = (f4*)(wlds + ROT_OFF);
        for (int i = lane; i < ROTF / 4; i += 64)
            dst[i] = __builtin_nontemporal_load(src + i);
    }
    // same-wave LDS RAW: DS ops complete in order per wave (lgkmcnt); no barrier

    const bool active = lane < J_;

    // ancestor pointer: virtual identity lane = 63 (self-loop)
    int anc = 63;
    if (active && lane > 0) anc = parents[lane];

    // local transform -> running composed (identity for lanes >= J_, incl. 63)
    float a0=1.f,a1=0.f,a2=0.f,a3=0.f,a4=1.f,a5=0.f,a6=0.f,a7=0.f,a8=1.f;
    float t0=0.f,t1=0.f,t2=0.f;
    if (active) {
        const float* rp = wlds + ROT_OFF + lane * 9;   // stride 9 dwords: conflict-free
        a0 = rp[0]; a1 = rp[1]; a2 = rp[2];
        a3 = rp[3]; a4 = rp[4]; a5 = rp[5];
        a6 = rp[6]; a7 = rp[7]; a8 = rp[8];
        if (lane == 0) {
            const float* pp = position + bt * 3;
            t0 = pp[0]; t1 = pp[1]; t2 = pp[2];
        } else {
            const float* op = offsets + ((long long)b * J_ + lane) * 3;
            t0 = op[0]; t1 = op[1]; t2 = op[2];
        }
    }

    // exact wave-uniform trip count: min r with anc_r(j)==63 for all j
    int rounds = 0;
    {
        int aa = anc;
        while (rounds < 8 && !__all(aa == 63)) { aa = __shfl(aa, aa); ++rounds; }
    }

    // pointer-jumping, branch-free (composition with lane 63 is identity)
    #pragma unroll 1
    for (int r = 0; r < rounds; ++r) {
        float p0 = __shfl(a0, anc), p1 = __shfl(a1, anc), p2 = __shfl(a2, anc);
        float p3 = __shfl(a3, anc), p4 = __shfl(a4, anc), p5 = __shfl(a5, anc);
        float p6 = __shfl(a6, anc), p7 = __shfl(a7, anc), p8 = __shfl(a8, anc);
        float q0 = __shfl(t0, anc), q1 = __shfl(t1, anc), q2 = __shfl(t2, anc);
        int   na = __shfl(anc, anc);

        float n0 = p0*a0 + p1*a3 + p2*a6;
        float n1 = p0*a1 + p1*a4 + p2*a7;
        float n2 = p0*a2 + p1*a5 + p2*a8;
        float n3 = p3*a0 + p4*a3 + p5*a6;
        float n4 = p3*a1 + p4*a4 + p5*a7;
        float n5 = p3*a2 + p4*a5 + p5*a8;
        float n6 = p6*a0 + p7*a3 + p8*a6;
        float n7 = p6*a1 + p7*a4 + p8*a7;
        float n8 = p6*a2 + p7*a5 + p8*a8;
        float m0 = p0*t0 + p1*t1 + p2*t2 + q0;
        float m1 = p3*t0 + p4*t1 + p5*t2 + q1;
        float m2 = p6*t0 + p7*t1 + p8*t2 + q2;

        a0=n0; a1=n1; a2=n2; a3=n3; a4=n4; a5=n5; a6=n6; a7=n7; a8=n8;
        t0=m0; t1=m1; t2=m2;
        anc = na;
    }

    // ---- composed -> own LDS slice (swizzled b128), positions -> own slice ----
    float* cmp = wlds + CMP_OFF;
    if (active) {
        const int base = lane * 64;   // local byte offset in composed slice
        *(float4*)((char*)cmp + swz(base +  0)) = make_float4(a0, a1, a2, t0);
        *(float4*)((char*)cmp + swz(base + 16)) = make_float4(a3, a4, a5, t1);
        *(float4*)((char*)cmp + swz(base + 32)) = make_float4(a6, a7, a8, t2);
        *(float4*)((char*)cmp + swz(base + 48)) = make_float4(0.f, 0.f, 0.f, 1.f);
        float* lp = wlds + POS_OFF + lane * 3;   // stride 3 dwords: conflict-free
        lp[0] = t0; lp[1] = t1; lp[2] = t2;
    }
    // same-wave in-order DS again; waves stream out independently

    // ---- stream both outputs, contiguous nontemporal f4, per wave ----
    {
        f4* cd = (f4*)(out_comp + bt * CMPF);
        for (int i = lane; i < CMPF / 4; i += 64) {
            f4 v = *(const f4*)((const char*)cmp + swz(i * 16));
            __builtin_nontemporal_store(v, cd + i);
        }
        f4* pd = (f4*)(out_pos + bt * POSF);
        const f4* ps4 = (const f4*)(wlds + POS_OFF);
        for (int i = lane; i < POSF / 4; i += 64)
            __builtin_nontemporal_store(ps4[i], pd + i);
    }
}

extern "C" void kernel_launch(void* const* d_in, const int* in_sizes, int n_in,
                              void* d_out, int out_size, void* d_ws, size_t ws_size,
                              hipStream_t stream) {
    const float* rotation = (const float*)d_in[0];
    const float* position = (const float*)d_in[1];
    const float* offsets  = (const float*)d_in[2];
    const int*   parents  = (const int*)d_in[3];

    float* out_pos  = (float*)d_out;                                  // (B,T,J,3)
    float* out_comp = (float*)d_out + (size_t)B_ * T_ * J_ * 3;       // (B,T,J,4,4)

    dim3 block(256);                        // 4 independent waves = 4 chains
    dim3 grid((B_ * T_) / CPB);             // 16384 blocks
    hipLaunchKernelGGL(ForwardKinematics_38543036514646_kernel, grid, block, 0, stream,
                       rotation, position, offsets, parents, out_pos, out_comp);
}

// Round 7
// 72.412 us; speedup vs baseline: 1.0130x; 1.0130x over previous
//
#include <hip/hip_runtime.h>

#define B_ 64
#define T_ 1024
#define J_ 52
#define CPB 8                       // chains (waves) per block
#define ROTF (J_ * 9)               // 468 floats per chain (local rotations)
#define CMPF (J_ * 16)              // 832 floats per chain (composed 4x4)
#define POSF (J_ * 3)               // 156 floats per chain (positions)
#define LDS_CMP (CPB * CMPF)        // 6656 floats = 26624 B
#define LDS_POS (CPB * POSF)        // 1248 floats =  4992 B
#define NTHREADS (CPB * 64)         // 512

typedef float f4 __attribute__((ext_vector_type(4)));   // nontemporal-builtin-compatible

// Involutive XOR swizzle: byte bits [4:5] ^= bits [7:8].
// Bijective within each 128B row, involution, keeps 16B alignment.
__device__ __forceinline__ int swz(int byte) {
    return byte ^ (((byte >> 7) & 3) << 4);
}

__global__ __launch_bounds__(NTHREADS) void ForwardKinematics_38543036514646_kernel(
    const float* __restrict__ rotation,   // (B,T,J,3,3)
    const float* __restrict__ position,   // (B,T,3)
    const float* __restrict__ offsets,    // (B,J,3)
    const int*   __restrict__ parents,    // (J,)
    float* __restrict__ out_pos,          // (B,T,J,3)
    float* __restrict__ out_comp)         // (B,T,J,4,4)
{
    __shared__ float lds[LDS_CMP + LDS_POS];   // rot staging reuses first CPB*ROTF floats

    const int tid  = threadIdx.x;
    const int lane = tid & 63;
    const int wv   = tid >> 6;
    const long long bt0 = (long long)blockIdx.x * CPB;
    const long long bt  = bt0 + wv;
    const int b = (int)(bt >> 10);   // T = 1024

    // ---- stage CPB chains of rotations into LDS, coalesced nontemporal f4 ----
    {
        const f4* src = (const f4*)(rotation + bt0 * ROTF);
        f4* dst = (f4*)lds;
        for (int i = tid; i < (CPB * ROTF) / 4; i += NTHREADS)
            dst[i] = __builtin_nontemporal_load(src + i);
    }
    __syncthreads();

    const bool active = lane < J_;

    // ancestor pointer: virtual identity lane = 63 (self-loop)
    int anc = 63;
    if (lane > 0 && active) anc = parents[lane];

    // local transform -> running composed (identity for lanes >= J_, incl. 63)
    float a0=1.f,a1=0.f,a2=0.f,a3=0.f,a4=1.f,a5=0.f,a6=0.f,a7=0.f,a8=1.f;
    float t0=0.f,t1=0.f,t2=0.f;
    if (active) {
        const float* rp = lds + wv * ROTF + lane * 9;   // stride 9 dwords: conflict-free
        a0 = rp[0]; a1 = rp[1]; a2 = rp[2];
        a3 = rp[3]; a4 = rp[4]; a5 = rp[5];
        a6 = rp[6]; a7 = rp[7]; a8 = rp[8];
        if (lane == 0) {
            const float* pp = position + bt * 3;
            t0 = pp[0]; t1 = pp[1]; t2 = pp[2];
        } else {
            const float* op = offsets + ((long long)b * J_ + lane) * 3;
            t0 = op[0]; t1 = op[1]; t2 = op[2];
        }
    }
    __syncthreads();   // rot LDS reads done; buffer overwritten by composed below

    // exact wave-uniform trip count: min r with anc_r(j)==63 for all j
    int rounds = 0;
    {
        int aa = anc;
        while (rounds < 8 && !__all(aa == 63)) { aa = __shfl(aa, aa); ++rounds; }
    }

    // pointer-jumping, branch-free (composition with lane 63 is identity)
    #pragma unroll 1
    for (int r = 0; r < rounds; ++r) {
        float p0 = __shfl(a0, anc), p1 = __shfl(a1, anc), p2 = __shfl(a2, anc);
        float p3 = __shfl(a3, anc), p4 = __shfl(a4, anc), p5 = __shfl(a5, anc);
        float p6 = __shfl(a6, anc), p7 = __shfl(a7, anc), p8 = __shfl(a8, anc);
        float q0 = __shfl(t0, anc), q1 = __shfl(t1, anc), q2 = __shfl(t2, anc);
        int   na = __shfl(anc, anc);

        float n0 = p0*a0 + p1*a3 + p2*a6;
        float n1 = p0*a1 + p1*a4 + p2*a7;
        float n2 = p0*a2 + p1*a5 + p2*a8;
        float n3 = p3*a0 + p4*a3 + p5*a6;
        float n4 = p3*a1 + p4*a4 + p5*a7;
        float n5 = p3*a2 + p4*a5 + p5*a8;
        float n6 = p6*a0 + p7*a3 + p8*a6;
        float n7 = p6*a1 + p7*a4 + p8*a7;
        float n8 = p6*a2 + p7*a5 + p8*a8;
        float m0 = p0*t0 + p1*t1 + p2*t2 + q0;
        float m1 = p3*t0 + p4*t1 + p5*t2 + q1;
        float m2 = p6*t0 + p7*t1 + p8*t2 + q2;

        a0=n0; a1=n1; a2=n2; a3=n3; a4=n4; a5=n5; a6=n6; a7=n7; a8=n8;
        t0=m0; t1=m1; t2=m2;
        anc = na;
    }

    // ---- composed -> LDS (swizzled b128 writes), positions -> LDS ----
    if (active) {
        const int base = (wv * CMPF + lane * 16) * 4;   // byte offset in composed buf
        *(float4*)((char*)lds + swz(base +  0)) = make_float4(a0, a1, a2, t0);
        *(float4*)((char*)lds + swz(base + 16)) = make_float4(a3, a4, a5, t1);
        *(float4*)((char*)lds + swz(base + 32)) = make_float4(a6, a7, a8, t2);
        *(float4*)((char*)lds + swz(base + 48)) = make_float4(0.f, 0.f, 0.f, 1.f);
        float* lp = lds + LDS_CMP + wv * POSF + lane * 3;  // stride 3: conflict-free
        lp[0] = t0; lp[1] = t1; lp[2] = t2;
    }
    __syncthreads();

    // ---- stream both outputs out, contiguous nontemporal f4 ----
    {
        f4* cd = (f4*)(out_comp + bt0 * CMPF);
        for (int i = tid; i < LDS_CMP / 4; i += NTHREADS) {
            f4 v = *(const f4*)((const char*)lds + swz(i * 16));
            __builtin_nontemporal_store(v, cd + i);
        }
        f4* pd = (f4*)(out_pos + bt0 * POSF);
        const f4* ps4 = (const f4*)(lds + LDS_CMP);
        for (int i = tid; i < LDS_POS / 4; i += NTHREADS)
            __builtin_nontemporal_store(ps4[i], pd + i);
    }
}

extern "C" void kernel_launch(void* const* d_in, const int* in_sizes, int n_in,
                              void* d_out, int out_size, void* d_ws, size_t ws_size,
                              hipStream_t stream) {
    const float* rotation = (const float*)d_in[0];
    const float* position = (const float*)d_in[1];
    const float* offsets  = (const float*)d_in[2];
    const int*   parents  = (const int*)d_in[3];

    float* out_pos  = (float*)d_out;                                  // (B,T,J,3)
    float* out_comp = (float*)d_out + (size_t)B_ * T_ * J_ * 3;       // (B,T,J,4,4)

    dim3 block(NTHREADS);                   // 8 waves = 8 chains per block
    dim3 grid((B_ * T_) / CPB);             // 8192 blocks
    hipLaunchKernelGGL(ForwardKinematics_38543036514646_kernel, grid, block, 0, stream,
                       rotation, position, offsets, parents, out_pos, out_comp);
}

// Round 8
// 70.314 us; speedup vs baseline: 1.0432x; 1.0298x over previous
//
#include <hip/hip_runtime.h>

#define B_ 64
#define T_ 1024
#define J_ 52
#define CPB 4                       // chains (waves) per block
#define ROTF (J_ * 9)               // 468 floats per chain (local rotations)
#define CMPF (J_ * 16)              // 832 floats per chain (composed 4x4)
#define POSF (J_ * 3)               // 156 floats per chain (positions)
#define LDS_CMP (CPB * CMPF)        // 3328 floats = 13312 B
#define LDS_POS (CPB * POSF)        // 624 floats  =  2496 B

typedef float f4 __attribute__((ext_vector_type(4)));   // nontemporal-builtin-compatible

// Involutive XOR swizzle: byte bits [4:5] ^= bits [7:8].
// Bijective, involution, keeps 16B alignment.
__device__ __forceinline__ int swz(int byte) {
    return byte ^ (((byte >> 7) & 3) << 4);
}

__global__ __launch_bounds__(256) void ForwardKinematics_38543036514646_kernel(
    const float* __restrict__ rotation,   // (B,T,J,3,3)
    const float* __restrict__ position,   // (B,T,3)
    const float* __restrict__ offsets,    // (B,J,3)
    const int*   __restrict__ parents,    // (J,)
    float* __restrict__ out_pos,          // (B,T,J,3)
    float* __restrict__ out_comp)         // (B,T,J,4,4)
{
    __shared__ float lds[LDS_CMP + LDS_POS];   // first 1872 floats reused for rot stage

    const int tid  = threadIdx.x;
    const int lane = tid & 63;
    const int wv   = tid >> 6;
    const long long bt0 = (long long)blockIdx.x * CPB;
    const long long bt  = bt0 + wv;
    const int b = (int)(bt >> 10);   // T = 1024

    // ---- stage CPB chains of rotations into LDS, coalesced nontemporal float4 ----
    {
        const f4* src = (const f4*)(rotation + bt0 * ROTF);
        f4* dst = (f4*)lds;
        for (int i = tid; i < (CPB * ROTF) / 4; i += 256)
            dst[i] = __builtin_nontemporal_load(src + i);
    }
    __syncthreads();

    const bool active = lane < J_;

    // ancestor pointer: virtual identity lane = 63 (self-loop)
    int anc = 63;
    if (lane > 0 && active) anc = parents[lane];

    // local transform -> running composed (identity for lanes >= J_, incl. 63)
    float a0=1.f,a1=0.f,a2=0.f,a3=0.f,a4=1.f,a5=0.f,a6=0.f,a7=0.f,a8=1.f;
    float t0=0.f,t1=0.f,t2=0.f;
    if (active) {
        const float* rp = lds + wv * ROTF + lane * 9;   // stride 9 dwords: conflict-free
        a0 = rp[0]; a1 = rp[1]; a2 = rp[2];
        a3 = rp[3]; a4 = rp[4]; a5 = rp[5];
        a6 = rp[6]; a7 = rp[7]; a8 = rp[8];
        if (lane == 0) {
            const float* pp = position + bt * 3;
            t0 = pp[0]; t1 = pp[1]; t2 = pp[2];
        } else {
            const float* op = offsets + ((long long)b * J_ + lane) * 3;
            t0 = op[0]; t1 = op[1]; t2 = op[2];
        }
    }
    __syncthreads();   // all rot LDS reads done; buffer will be overwritten below

    // exact wave-uniform trip count: min r with anc_r(j)==63 for all j
    int rounds = 0;
    {
        int aa = anc;
        while (rounds < 8 && !__all(aa == 63)) { aa = __shfl(aa, aa); ++rounds; }
    }

    // pointer-jumping, branch-free (composition with lane 63 is identity)
    #pragma unroll 1
    for (int r = 0; r < rounds; ++r) {
        float p0 = __shfl(a0, anc), p1 = __shfl(a1, anc), p2 = __shfl(a2, anc);
        float p3 = __shfl(a3, anc), p4 = __shfl(a4, anc), p5 = __shfl(a5, anc);
        float p6 = __shfl(a6, anc), p7 = __shfl(a7, anc), p8 = __shfl(a8, anc);
        float q0 = __shfl(t0, anc), q1 = __shfl(t1, anc), q2 = __shfl(t2, anc);
        int   na = __shfl(anc, anc);

        float n0 = p0*a0 + p1*a3 + p2*a6;
        float n1 = p0*a1 + p1*a4 + p2*a7;
        float n2 = p0*a2 + p1*a5 + p2*a8;
        float n3 = p3*a0 + p4*a3 + p5*a6;
        float n4 = p3*a1 + p4*a4 + p5*a7;
        float n5 = p3*a2 + p4*a5 + p5*a8;
        float n6 = p6*a0 + p7*a3 + p8*a6;
        float n7 = p6*a1 + p7*a4 + p8*a7;
        float n8 = p6*a2 + p7*a5 + p8*a8;
        float m0 = p0*t0 + p1*t1 + p2*t2 + q0;
        float m1 = p3*t0 + p4*t1 + p5*t2 + q1;
        float m2 = p6*t0 + p7*t1 + p8*t2 + q2;

        a0=n0; a1=n1; a2=n2; a3=n3; a4=n4; a5=n5; a6=n6; a7=n7; a8=n8;
        t0=m0; t1=m1; t2=m2;
        anc = na;
    }

    // ---- composed -> LDS (swizzled b128 writes), positions -> LDS ----
    if (active) {
        const int base = (wv * CMPF + lane * 16) * 4;   // byte offset in composed buf
        *(float4*)((char*)lds + swz(base +  0)) = make_float4(a0, a1, a2, t0);
        *(float4*)((char*)lds + swz(base + 16)) = make_float4(a3, a4, a5, t1);
        *(float4*)((char*)lds + swz(base + 32)) = make_float4(a6, a7, a8, t2);
        *(float4*)((char*)lds + swz(base + 48)) = make_float4(0.f, 0.f, 0.f, 1.f);
        float* lp = lds + LDS_CMP + wv * POSF + lane * 3;  // stride 3: conflict-free
        lp[0] = t0; lp[1] = t1; lp[2] = t2;
    }
    __syncthreads();

    // ---- stream both outputs out, contiguous nontemporal float4 ----
    {
        f4* cd = (f4*)(out_comp + bt0 * CMPF);
        for (int i = tid; i < LDS_CMP / 4; i += 256) {
            f4 v = *(const f4*)((const char*)lds + swz(i * 16));
            __builtin_nontemporal_store(v, cd + i);
        }
        f4* pd = (f4*)(out_pos + bt0 * POSF);
        const f4* ps4 = (const f4*)(lds + LDS_CMP);
        for (int i = tid; i < LDS_POS / 4; i += 256)
            __builtin_nontemporal_store(ps4[i], pd + i);
    }
}

extern "C" void kernel_launch(void* const* d_in, const int* in_sizes, int n_in,
                              void* d_out, int out_size, void* d_ws, size_t ws_size,
                              hipStream_t stream) {
    const float* rotation = (const float*)d_in[0];
    const float* position = (const float*)d_in[1];
    const float* offsets  = (const float*)d_in[2];
    const int*   parents  = (const int*)d_in[3];

    float* out_pos  = (float*)d_out;                                  // (B,T,J,3)
    float* out_comp = (float*)d_out + (size_t)B_ * T_ * J_ * 3;       // (B,T,J,4,4)

    dim3 block(256);                        // 4 waves = 4 chains per block
    dim3 grid((B_ * T_) / CPB);             // 16384 blocks
    hipLaunchKernelGGL(ForwardKinematics_38543036514646_kernel, grid, block, 0, stream,
                       rotation, position, offsets, parents, out_pos, out_comp);
}